// Round 11
// baseline (2260.695 us; speedup 1.0000x reference)
//
#include <hip/hip_runtime.h>
#include <hip/hip_bf16.h>
#include <math.h>

// ---------------------------------------------------------------------------
// GCN anomaly detector.
// Round 10 fix: passive per-node sorted walk gave ZERO locality (FETCH
// 165MB unchanged) -- one node's ~32 sorted edges still span the whole src
// table; locality needs cross-node time-concentration. Round 11: aggs are
// now EDGE-PARALLEL per dst-bucket: fp32 accumulators in LDS (256 nodes x
// D, padded stride), edges consumed in ascending-src order (sorted in
// bucketprep), ~391 blocks all co-resident sweeping the feature table in
// loose sync (round-9 locality + round-8 MLP). csr/rs/cnt eliminated.
// Assumes N <= 131072 (bucket = 256 nodes, src fits 24 bits): here N=100k.
// ---------------------------------------------------------------------------

__global__ void k_detect(const unsigned int* __restrict__ w, int npairs,
                         int* __restrict__ meta) {
  __shared__ int any;
  if (threadIdx.x == 0) any = 0;
  __syncthreads();
  int local = 0;
  for (int i = threadIdx.x; i < npairs; i += blockDim.x)
    local |= (w[2 * i + 1] != 0u);
  if (local) atomicOr(&any, 1);
  __syncthreads();
  if (threadIdx.x == 0) meta[0] = any ? 0 : 1;  // 1 => edge_index is int64
}

// P1: per-chunk LDS histogram over dst buckets. hist layout: [bin][chunk].
__global__ __launch_bounds__(256) void k_binhist(const void* __restrict__ ei,
                                                 int E, int CS, int B, int shift,
                                                 const int* __restrict__ meta,
                                                 int* __restrict__ hist, int C) {
  __shared__ int lh[512];
  int c = blockIdx.x;
  for (int i = threadIdx.x; i < B; i += 256) lh[i] = 0;
  __syncthreads();
  int e0 = c * CS, e1 = min(E, e0 + CS);
  bool is64 = meta[0] != 0;
  for (int e = e0 + threadIdx.x; e < e1; e += 256) {
    int d = is64 ? (int)((const long long*)ei)[(long)E + e]
                 : ((const int*)ei)[(long)E + e];
    atomicAdd(&lh[d >> shift], 1);
  }
  __syncthreads();
  for (int b = threadIdx.x; b < B; b += 256) hist[(long)b * C + c] = lh[b];
}

// P3: re-read edges, write packed (dstInBucket<<SB | src) into reserved
// per-(chunk,bin) ranges. LDS cursors only -> zero global atomics.
__global__ __launch_bounds__(256) void k_binscatter(const void* __restrict__ ei,
                                                    int E, int CS, int B, int shift,
                                                    int SB,
                                                    const int* __restrict__ meta,
                                                    const int* __restrict__ scan,
                                                    int C, unsigned* __restrict__ pairs) {
  __shared__ int cur[512];
  int c = blockIdx.x;
  for (int b = threadIdx.x; b < B; b += 256) cur[b] = scan[(long)b * C + c];
  __syncthreads();
  int e0 = c * CS, e1 = min(E, e0 + CS);
  bool is64 = meta[0] != 0;
  unsigned spb1 = (1u << shift) - 1u;
  for (int e = e0 + threadIdx.x; e < e1; e += 256) {
    int s, d;
    if (is64) {
      const long long* p = (const long long*)ei;
      s = (int)p[e]; d = (int)p[(long)E + e];
    } else {
      const int* p = (const int*)ei;
      s = p[e]; d = p[(long)E + e];
    }
    int pos = atomicAdd(&cur[d >> shift], 1);
    pairs[pos] = (((unsigned)d & spb1) << SB) | (unsigned)s;
  }
}

// P4: per-bucket: dst-degree hist -> dis; in-LDS counting sort of the
// bucket's pairs by src-bin (src>>S2), written back IN PLACE (block owns
// its range). Overflow -> skip sort (still correct, just less locality).
#define BB_CAP 12288
__global__ __launch_bounds__(256) void k_bucketprep(unsigned* __restrict__ pairs,
                                                    const int* __restrict__ scan,
                                                    int C, int shift, int SB, int S2,
                                                    int N, float* __restrict__ dis) {
  __shared__ unsigned buf[BB_CAP];    // 48 KB
  __shared__ unsigned buf2[BB_CAP];   // 48 KB
  __shared__ int h[256];
  __shared__ int sm[256];
  __shared__ int sh[512];
  int bin = blockIdx.x;
  int base = bin << shift;
  int nn = min(N - base, 1 << shift);
  int t = threadIdx.x;
  unsigned smask = (1u << SB) - 1u;
  int p0 = scan[(long)bin * C];
  int p1 = scan[(long)(bin + 1) * C];  // sentinel gives E for last bucket
  int ne = p1 - p0;
  bool srt = (ne <= BB_CAP);

  if (srt)
    for (int i = t; i < ne; i += 256) buf[i] = pairs[p0 + i];
  h[t] = 0;
  __syncthreads();
  for (int i = t; i < ne; i += 256)
    atomicAdd(&h[(srt ? buf[i] : pairs[p0 + i]) >> SB], 1);
  __syncthreads();
  if (t < nn) dis[base + t] = rsqrtf((float)h[t] + 1.0f);

  if (srt) {
    for (int i = t; i < 512; i += 256) sh[i] = 0;
    __syncthreads();
    for (int i = t; i < ne; i += 256)
      atomicAdd(&sh[(buf[i] & smask) >> S2], 1);
    __syncthreads();
    int a0 = sh[2 * t], a1 = sh[2 * t + 1];
    int ss = a0 + a1;
    sm[t] = ss;
    __syncthreads();
    for (int off = 1; off < 256; off <<= 1) {
      int x = (t >= off) ? sm[t - off] : 0;
      __syncthreads();
      sm[t] += x;
      __syncthreads();
    }
    int rn = sm[t] - ss;
    sh[2 * t] = rn; sh[2 * t + 1] = rn + a0;
    __syncthreads();
    for (int i = t; i < ne; i += 256) {
      unsigned p = buf[i];
      int pos = atomicAdd(&sh[(p & smask) >> S2], 1);
      buf2[pos] = p;
    }
    __syncthreads();
    for (int i = t; i < ne; i += 256) pairs[p0 + i] = buf2[i];
  }
}

__global__ __launch_bounds__(1024) void k_scan1(const int* __restrict__ cnt,
                                                int* __restrict__ bsums, int n) {
  __shared__ int sm[1024];
  int t = threadIdx.x;
  long i = (long)blockIdx.x * 1024 + t;
  sm[t] = (i < n) ? cnt[i] : 0;
  __syncthreads();
  for (int s = 512; s > 0; s >>= 1) {
    if (t < s) sm[t] += sm[t + s];
    __syncthreads();
  }
  if (t == 0) bsums[blockIdx.x] = sm[0];
}

__global__ void k_scan2(int* __restrict__ bsums, int nb) {
  __shared__ int sm[256];
  int t = threadIdx.x;
  int v = (t < nb) ? bsums[t] : 0;
  sm[t] = v;
  __syncthreads();
  for (int off = 1; off < 256; off <<= 1) {
    int x = (t >= off) ? sm[t - off] : 0;
    __syncthreads();
    sm[t] += x;
    __syncthreads();
  }
  if (t < nb) bsums[t] = sm[t] - v;  // exclusive
}

// exclusive scan -> out (may alias in); optional sentinel out[n] = total.
__global__ __launch_bounds__(1024) void k_scan3s(const int* __restrict__ in,
                                                 const int* __restrict__ bsums,
                                                 int* __restrict__ out, int n,
                                                 int sentinel) {
  __shared__ int sm[1024];
  int t = threadIdx.x;
  long i = (long)blockIdx.x * 1024 + t;
  int v = (i < n) ? in[i] : 0;
  sm[t] = v;
  __syncthreads();
  for (int off = 1; off < 1024; off <<= 1) {
    int x = (t >= off) ? sm[t - off] : 0;
    __syncthreads();
    sm[t] += x;
    __syncthreads();
  }
  int excl = sm[t] - v + bsums[blockIdx.x];
  if (i < n) out[i] = excl;
  if (sentinel && i == n - 1) out[n] = excl + v;
}

__device__ __forceinline__ float bfu(unsigned short u) {
  return __uint_as_float((unsigned)u << 16);
}
__device__ __forceinline__ float bf_lo(unsigned u) {
  return __uint_as_float(u << 16);
}
__device__ __forceinline__ float bf_hi(unsigned u) {
  return __uint_as_float(u & 0xffff0000u);
}
__device__ __forceinline__ unsigned pack_bf2(float lo, float hi) {
  __hip_bfloat16 a = __float2bfloat16(lo), b = __float2bfloat16(hi);
  return (unsigned)*(unsigned short*)&a | ((unsigned)*(unsigned short*)&b << 16);
}

// C[n, M] = act(A[n, K] @ W[K, M] (+ bias)); W row-major [K][M], staged in LDS.
// K-loop pinned to no-unroll + manual next-k prefetch.
// ABF16: A rows are bf16. OBF16: write output as bf16 (RNE).
template <int K, int M, bool BIAS, int ACT, bool ABF16, bool OBF16>
__global__ __launch_bounds__(256) void k_gemm(const void* __restrict__ Av,
                                              const float* __restrict__ W,
                                              const float* __restrict__ bias,
                                              void* __restrict__ Cout, int nrows) {
  constexpr int CP = 4;
  constexpr int TPR = M / CP;        // threads per row
  constexpr int RG = 256 / TPR;      // row-groups per block
  constexpr int RP = 4;              // rows per thread
  constexpr int RT = RG * RP;        // rows per block
  __shared__ __align__(16) float sW[K * M];
  __shared__ __align__(16) float sB[BIAS ? M : 4];

  for (int i = threadIdx.x; i < K * M / 4; i += 256)
    ((float4*)sW)[i] = ((const float4*)W)[i];
  if (BIAS)
    for (int i = threadIdx.x; i < M; i += 256) sB[i] = bias[i];
  __syncthreads();

  const int cg = threadIdx.x % TPR;
  const int rg = threadIdx.x / TPR;
  const long row0 = (long)blockIdx.x * RT + rg;

  const float4* Apf[RP];
  const ushort4* Apb[RP];
  bool valid[RP];
#pragma unroll
  for (int r = 0; r < RP; ++r) {
    long row = row0 + (long)r * RG;
    valid[r] = (row < nrows);
    long rr = valid[r] ? row : 0;
    if (ABF16) Apb[r] = (const ushort4*)((const unsigned short*)Av + rr * K);
    else       Apf[r] = (const float4*)((const float*)Av + rr * K);
  }

  auto loadA = [&](int r, int k4) -> float4 {
    if (!valid[r]) return make_float4(0.f, 0.f, 0.f, 0.f);
    if (ABF16) {
      ushort4 q = Apb[r][k4];
      return make_float4(bfu(q.x), bfu(q.y), bfu(q.z), bfu(q.w));
    }
    return Apf[r][k4];
  };

  float acc[RP][CP] = {};
  float4 a[RP];
#pragma unroll
  for (int r = 0; r < RP; ++r) a[r] = loadA(r, 0);

#pragma unroll 1
  for (int k0 = 0; k0 < K - 4; k0 += 4) {
    float4 an[RP];
#pragma unroll
    for (int r = 0; r < RP; ++r) an[r] = loadA(r, k0 / 4 + 1);
#pragma unroll
    for (int j = 0; j < 4; ++j) {
      float4 w = ((const float4*)(sW + (k0 + j) * M))[cg];
#pragma unroll
      for (int r = 0; r < RP; ++r) {
        float av = (j == 0) ? a[r].x : (j == 1) ? a[r].y : (j == 2) ? a[r].z : a[r].w;
        acc[r][0] += av * w.x;
        acc[r][1] += av * w.y;
        acc[r][2] += av * w.z;
        acc[r][3] += av * w.w;
      }
    }
#pragma unroll
    for (int r = 0; r < RP; ++r) a[r] = an[r];
  }
  {  // last k-step
    const int k0 = K - 4;
#pragma unroll
    for (int j = 0; j < 4; ++j) {
      float4 w = ((const float4*)(sW + (k0 + j) * M))[cg];
#pragma unroll
      for (int r = 0; r < RP; ++r) {
        float av = (j == 0) ? a[r].x : (j == 1) ? a[r].y : (j == 2) ? a[r].z : a[r].w;
        acc[r][0] += av * w.x;
        acc[r][1] += av * w.y;
        acc[r][2] += av * w.z;
        acc[r][3] += av * w.w;
      }
    }
  }

#pragma unroll
  for (int r = 0; r < RP; ++r) {
    long row = row0 + (long)r * RG;
    if (row >= nrows) continue;
    float4 o = make_float4(acc[r][0], acc[r][1], acc[r][2], acc[r][3]);
    if (BIAS) {
      float4 bb = ((const float4*)sB)[cg];
      o.x += bb.x; o.y += bb.y; o.z += bb.z; o.w += bb.w;
    }
    if (ACT == 1) {
      o.x = fmaxf(o.x, 0.f); o.y = fmaxf(o.y, 0.f);
      o.z = fmaxf(o.z, 0.f); o.w = fmaxf(o.w, 0.f);
    }
    if (OBF16) {
      uint2 pk;
      pk.x = pack_bf2(o.x, o.y);
      pk.y = pack_bf2(o.z, o.w);
      ((uint2*)((__hip_bfloat16*)Cout + row * M))[cg] = pk;
    } else {
      ((float4*)((float*)Cout + row * M))[cg] = o;
    }
  }
}

// Edge-parallel agg, D=64: one block per dst-bucket (256 nodes), fp32 acc in
// LDS [256][65] (padded). 512 threads = 16 groups x 32 lanes; each group
// does one edge per step in ascending-src order (4x unrolled). Epilogue adds
// self-loop + bias, relu, writes packed bf16.
__global__ __launch_bounds__(512) void k_agg64e(const unsigned* __restrict__ hwu,
                                                const unsigned* __restrict__ pairs,
                                                const int* __restrict__ scan,
                                                int C, int shift, int SB,
                                                const float* __restrict__ dis,
                                                const float* __restrict__ b,
                                                unsigned* __restrict__ outu, int N) {
  __shared__ float acc[256 * 65];   // 66.6 KB
  __shared__ float disD[256];
  int bin = blockIdx.x;
  int base = bin << shift;
  int nn = min(N - base, 1 << shift);
  int t = threadIdx.x;
  for (int i = t; i < 256 * 65; i += 512) acc[i] = 0.f;
  if (t < 256) disD[t] = (t < nn) ? dis[base + t] : 0.f;
  __syncthreads();
  unsigned smask = (1u << SB) - 1u;
  int p0 = scan[(long)bin * C];
  int p1 = scan[(long)(bin + 1) * C];
  const int NG = 16;
  int gid = t >> 5;
  int lane = t & 31;
  int i = p0 + gid;
  for (; i + 3 * NG < p1; i += 4 * NG) {
    unsigned pr0 = pairs[i];
    unsigned pr1 = pairs[i + NG];
    unsigned pr2 = pairs[i + 2 * NG];
    unsigned pr3 = pairs[i + 3 * NG];
    unsigned s0 = pr0 & smask, d0 = pr0 >> SB;
    unsigned s1 = pr1 & smask, d1 = pr1 >> SB;
    unsigned s2 = pr2 & smask, d2 = pr2 >> SB;
    unsigned s3 = pr3 & smask, d3 = pr3 >> SB;
    unsigned q0 = hwu[s0 * 32u + lane];
    unsigned q1 = hwu[s1 * 32u + lane];
    unsigned q2 = hwu[s2 * 32u + lane];
    unsigned q3 = hwu[s3 * 32u + lane];
    float w0 = dis[s0] * disD[d0];
    float w1 = dis[s1] * disD[d1];
    float w2 = dis[s2] * disD[d2];
    float w3 = dis[s3] * disD[d3];
    atomicAdd(&acc[d0 * 65 + 2 * lane],     bf_lo(q0) * w0);
    atomicAdd(&acc[d0 * 65 + 2 * lane + 1], bf_hi(q0) * w0);
    atomicAdd(&acc[d1 * 65 + 2 * lane],     bf_lo(q1) * w1);
    atomicAdd(&acc[d1 * 65 + 2 * lane + 1], bf_hi(q1) * w1);
    atomicAdd(&acc[d2 * 65 + 2 * lane],     bf_lo(q2) * w2);
    atomicAdd(&acc[d2 * 65 + 2 * lane + 1], bf_hi(q2) * w2);
    atomicAdd(&acc[d3 * 65 + 2 * lane],     bf_lo(q3) * w3);
    atomicAdd(&acc[d3 * 65 + 2 * lane + 1], bf_hi(q3) * w3);
  }
  for (; i < p1; i += NG) {
    unsigned pr = pairs[i];
    unsigned s = pr & smask, d = pr >> SB;
    unsigned q = hwu[s * 32u + lane];
    float w = dis[s] * disD[d];
    atomicAdd(&acc[d * 65 + 2 * lane],     bf_lo(q) * w);
    atomicAdd(&acc[d * 65 + 2 * lane + 1], bf_hi(q) * w);
  }
  __syncthreads();
  for (int idx = t; idx < nn * 32; idx += 512) {
    int node = idx >> 5, u = idx & 31;
    unsigned q = hwu[(unsigned)(base + node) * 32u + u];
    float dd = disD[node] * disD[node];
    float o0 = acc[node * 65 + 2 * u]     + bf_lo(q) * dd + b[2 * u];
    float o1 = acc[node * 65 + 2 * u + 1] + bf_hi(q) * dd + b[2 * u + 1];
    outu[(unsigned)(base + node) * 32u + u] =
        pack_bf2(fmaxf(o0, 0.f), fmaxf(o1, 0.f));
  }
}

// Edge-parallel agg, D=32: acc [256][33], 512 threads = 32 groups x 16 lanes.
// fp32 output (this IS the h output in d_out). No relu.
__global__ __launch_bounds__(512) void k_agg32e(const unsigned* __restrict__ hwu,
                                                const unsigned* __restrict__ pairs,
                                                const int* __restrict__ scan,
                                                int C, int shift, int SB,
                                                const float* __restrict__ dis,
                                                const float* __restrict__ b,
                                                float* __restrict__ out, int N) {
  __shared__ float acc[256 * 33];   // 33.8 KB
  __shared__ float disD[256];
  int bin = blockIdx.x;
  int base = bin << shift;
  int nn = min(N - base, 1 << shift);
  int t = threadIdx.x;
  for (int i = t; i < 256 * 33; i += 512) acc[i] = 0.f;
  if (t < 256) disD[t] = (t < nn) ? dis[base + t] : 0.f;
  __syncthreads();
  unsigned smask = (1u << SB) - 1u;
  int p0 = scan[(long)bin * C];
  int p1 = scan[(long)(bin + 1) * C];
  const int NG = 32;
  int gid = t >> 4;
  int lane = t & 15;
  int i = p0 + gid;
  for (; i + 3 * NG < p1; i += 4 * NG) {
    unsigned pr0 = pairs[i];
    unsigned pr1 = pairs[i + NG];
    unsigned pr2 = pairs[i + 2 * NG];
    unsigned pr3 = pairs[i + 3 * NG];
    unsigned s0 = pr0 & smask, d0 = pr0 >> SB;
    unsigned s1 = pr1 & smask, d1 = pr1 >> SB;
    unsigned s2 = pr2 & smask, d2 = pr2 >> SB;
    unsigned s3 = pr3 & smask, d3 = pr3 >> SB;
    unsigned q0 = hwu[s0 * 16u + lane];
    unsigned q1 = hwu[s1 * 16u + lane];
    unsigned q2 = hwu[s2 * 16u + lane];
    unsigned q3 = hwu[s3 * 16u + lane];
    float w0 = dis[s0] * disD[d0];
    float w1 = dis[s1] * disD[d1];
    float w2 = dis[s2] * disD[d2];
    float w3 = dis[s3] * disD[d3];
    atomicAdd(&acc[d0 * 33 + 2 * lane],     bf_lo(q0) * w0);
    atomicAdd(&acc[d0 * 33 + 2 * lane + 1], bf_hi(q0) * w0);
    atomicAdd(&acc[d1 * 33 + 2 * lane],     bf_lo(q1) * w1);
    atomicAdd(&acc[d1 * 33 + 2 * lane + 1], bf_hi(q1) * w1);
    atomicAdd(&acc[d2 * 33 + 2 * lane],     bf_lo(q2) * w2);
    atomicAdd(&acc[d2 * 33 + 2 * lane + 1], bf_hi(q2) * w2);
    atomicAdd(&acc[d3 * 33 + 2 * lane],     bf_lo(q3) * w3);
    atomicAdd(&acc[d3 * 33 + 2 * lane + 1], bf_hi(q3) * w3);
  }
  for (; i < p1; i += NG) {
    unsigned pr = pairs[i];
    unsigned s = pr & smask, d = pr >> SB;
    unsigned q = hwu[s * 16u + lane];
    float w = dis[s] * disD[d];
    atomicAdd(&acc[d * 33 + 2 * lane],     bf_lo(q) * w);
    atomicAdd(&acc[d * 33 + 2 * lane + 1], bf_hi(q) * w);
  }
  __syncthreads();
  for (int idx = t; idx < nn * 16; idx += 512) {
    int node = idx >> 4, u = idx & 15;
    unsigned q = hwu[(unsigned)(base + node) * 16u + u];
    float dd = disD[node] * disD[node];
    float o0 = acc[node * 33 + 2 * u]     + bf_lo(q) * dd + b[2 * u];
    float o1 = acc[node * 33 + 2 * u + 1] + bf_hi(q) * dd + b[2 * u + 1];
    ((float2*)(out + (unsigned)(base + node) * 32u))[u] = make_float2(o0, o1);
  }
}

// score = sigmoid(s[N,32] @ sW2[32] + sb2); 8 nodes per 256-thread block.
__global__ void k_score(const float* __restrict__ s, const float* __restrict__ sW2,
                        const float* __restrict__ sb2, float* __restrict__ out, int n) {
  int node = blockIdx.x * 8 + (threadIdx.x >> 5);
  int k = threadIdx.x & 31;
  if (node >= n) return;
  float v = s[(long)node * 32 + k] * sW2[k];
  for (int off = 16; off > 0; off >>= 1) v += __shfl_down(v, off, 32);
  if (k == 0) out[node] = 1.0f / (1.0f + expf(-(v + sb2[0])));
}

extern "C" void kernel_launch(void* const* d_in, const int* in_sizes, int n_in,
                              void* d_out, int out_size, void* d_ws, size_t ws_size,
                              hipStream_t stream) {
  const float* x   = (const float*)d_in[0];
  const void*  ei  = d_in[1];
  const float* W1  = (const float*)d_in[2];
  const float* b1  = (const float*)d_in[3];
  const float* W2  = (const float*)d_in[4];
  const float* b2  = (const float*)d_in[5];
  const float* rW1 = (const float*)d_in[6];
  const float* rb1 = (const float*)d_in[7];
  const float* rW2 = (const float*)d_in[8];
  const float* rb2 = (const float*)d_in[9];
  const float* sW1 = (const float*)d_in[10];
  const float* sb1 = (const float*)d_in[11];
  const float* sW2 = (const float*)d_in[12];
  const float* sb2 = (const float*)d_in[13];

  const int N = in_sizes[0] / 128;
  const int E = in_sizes[1] / 2;

  // bucket geometry: 256 nodes/bucket (N <= 131072 assumed; here N=100k)
  const int shift = 8;
  const int SB = 24;                       // src bits in packed pair
  const int S2 = 8;                        // src sort-bin shift (<512 bins)
  const int B = (N + 255) >> 8;            // dst buckets (<=512)
  const int C = 512;                       // edge chunks
  const int CS = (E + C - 1) / C;          // edges per chunk
  const int L = B * C;

  // workspace layout (256B aligned chunks)
  char* w = (char*)d_ws;
  auto alloc = [&](size_t bytes) {
    char* p = w;
    w += (bytes + 255) & ~(size_t)255;
    return p;
  };
  int*   meta   = (int*)alloc(64);
  float* dis    = (float*)alloc((size_t)N * 4);
  int*   bsumsL = (int*)alloc(1024);
  int*   bscan  = (int*)alloc(((size_t)L + 1) * 4);
  // union buffer: pairs (E*4B packed) -> later tbuf bf16 [N,64] / sbuf fp32 [N,32]
  size_t uni = (size_t)E * 4 > (size_t)N * 128 ? (size_t)E * 4 : (size_t)N * 128;
  char*  u      = alloc(uni);
  unsigned* pairs = (unsigned*)u;
  __hip_bfloat16* tbuf = (__hip_bfloat16*)u;   // recon intermediate [N,64] bf16
  float* sbuf   = (float*)u;                   // scorer intermediate [N,32] fp32
  unsigned* hw1 = (unsigned*)alloc((size_t)N * 64 * 2);  // bf16 [N][64] = [N][32 uints]
  unsigned* h1  = (unsigned*)alloc((size_t)N * 64 * 2);  // bf16 [N][64]
  unsigned* hw2 = (unsigned*)alloc((size_t)N * 32 * 2);  // bf16 [N][32] = [N][16 uints]

  float* h_out = (float*)d_out;                 // [N,32]
  float* x_rec = h_out + (long)N * 32;          // [N,128]
  float* score = x_rec + (long)N * 128;         // [N,1]

  // ---- edge bucketing (atomic-free counting sort; pairs end src-sorted) ----
  k_detect<<<1, 256, 0, stream>>>((const unsigned int*)ei, E < 4096 ? E : 4096, meta);
  k_binhist<<<C, 256, 0, stream>>>(ei, E, CS, B, shift, meta, bscan, C);
  int nbL = (L + 1023) / 1024;
  k_scan1<<<nbL, 1024, 0, stream>>>(bscan, bsumsL, L);
  k_scan2<<<1, 256, 0, stream>>>(bsumsL, nbL);
  k_scan3s<<<nbL, 1024, 0, stream>>>(bscan, bsumsL, bscan, L, 1);  // in-place + sentinel
  k_binscatter<<<C, 256, 0, stream>>>(ei, E, CS, B, shift, SB, meta, bscan, C, pairs);
  k_bucketprep<<<B, 256, 0, stream>>>(pairs, bscan, C, shift, SB, S2, N, dis);

  // ---- layer 1: hw1 = bf16(x @ W1) ; h1 = bf16(relu(agg + b1)) ----
  k_gemm<128, 64, false, 0, false, true><<<(N + 63) / 64, 256, 0, stream>>>(x, W1, nullptr, hw1, N);
  k_agg64e<<<B, 512, 0, stream>>>(hw1, pairs, bscan, C, shift, SB, dis, b1, h1, N);

  // ---- layer 2: hw2 = bf16(h1 @ W2) ; h = agg + b2 -> d_out ----
  k_gemm<64, 32, false, 0, true, true><<<(N + 127) / 128, 256, 0, stream>>>(h1, W2, nullptr, hw2, N);
  k_agg32e<<<B, 512, 0, stream>>>(hw2, pairs, bscan, C, shift, SB, dis, b2, h_out, N);

  // ---- reconstruction MLP: t = bf16(relu(h@rW1+rb1)) ; x_rec = t@rW2+rb2 ----
  k_gemm<32, 64, true, 1, false, true><<<(N + 63) / 64, 256, 0, stream>>>(h_out, rW1, rb1, tbuf, N);
  k_gemm<64, 128, true, 0, true, false><<<(N + 31) / 32, 256, 0, stream>>>(tbuf, rW2, rb2, x_rec, N);

  // ---- scorer MLP: s = relu(h@sW1+sb1) ; score = sigmoid(s@sW2+sb2) ----
  k_gemm<32, 32, true, 1, false, false><<<(N + 127) / 128, 256, 0, stream>>>(h_out, sW1, sb1, sbuf, N);
  k_score<<<(N + 7) / 8, 256, 0, stream>>>(sbuf, sW2, sb2, score, N);
}

// Round 12
// 531.351 us; speedup vs baseline: 4.2546x; 4.2546x over previous
//
#include <hip/hip_runtime.h>
#include <hip/hip_bf16.h>
#include <math.h>

// ---------------------------------------------------------------------------
// GCN anomaly detector.
// Round 11 post-mortem: edge-parallel LDS-atomic agg was a 7x regression
// (205M LDS atomic RMWs, bank contention, 26% occupancy). Reverted to the
// round-8 register-accumulation structure.
// Round 12: XCD FEATURE-SLICING for the layer-1 agg (the 62us top kernel).
// hw1 stored slice-major [8][N][16B]; block b handles feature-slice (b&7)
// and a 512-node range. With round-robin block->XCD dispatch, slice k lives
// on XCD k: working set 1.6MB << 4MB L2 -> all gathers L2-hit; compulsory
// feature traffic 12.8MB (vs 165MB measured round-8/10). Same instruction
// structure as round-8 (4-lane groups, unroll 8, register acc). h1 is also
// slice-major (coalesced per-slice writes); GEMM2 reads it via an ASLICE
// bf16 A-reader. XCD mapping is a perf heuristic only -- any mapping is
// correct. Layer-2 agg unchanged (round-8 style).
// ---------------------------------------------------------------------------

__global__ void k_detect(const unsigned int* __restrict__ w, int npairs,
                         int* __restrict__ meta) {
  __shared__ int any;
  if (threadIdx.x == 0) any = 0;
  __syncthreads();
  int local = 0;
  for (int i = threadIdx.x; i < npairs; i += blockDim.x)
    local |= (w[2 * i + 1] != 0u);
  if (local) atomicOr(&any, 1);
  __syncthreads();
  if (threadIdx.x == 0) meta[0] = any ? 0 : 1;  // 1 => edge_index is int64
}

// P1: per-chunk LDS histogram over dst buckets. hist layout: [bin][chunk].
__global__ __launch_bounds__(256) void k_binhist(const void* __restrict__ ei,
                                                 int E, int CS, int B, int shift,
                                                 const int* __restrict__ meta,
                                                 int* __restrict__ hist, int C) {
  __shared__ int lh[256];
  int c = blockIdx.x;
  for (int i = threadIdx.x; i < B; i += 256) lh[i] = 0;
  __syncthreads();
  int e0 = c * CS, e1 = min(E, e0 + CS);
  bool is64 = meta[0] != 0;
  for (int e = e0 + threadIdx.x; e < e1; e += 256) {
    int d = is64 ? (int)((const long long*)ei)[(long)E + e]
                 : ((const int*)ei)[(long)E + e];
    atomicAdd(&lh[d >> shift], 1);
  }
  __syncthreads();
  for (int b = threadIdx.x; b < B; b += 256) hist[(long)b * C + c] = lh[b];
}

// P3: re-read edges, write packed (dstInBucket<<SB | src) into reserved
// per-(chunk,bin) ranges. LDS cursors only -> zero global atomics.
__global__ __launch_bounds__(256) void k_binscatter(const void* __restrict__ ei,
                                                    int E, int CS, int B, int shift,
                                                    int SB,
                                                    const int* __restrict__ meta,
                                                    const int* __restrict__ scan,
                                                    int C, unsigned* __restrict__ pairs) {
  __shared__ int cur[256];
  int c = blockIdx.x;
  for (int b = threadIdx.x; b < B; b += 256) cur[b] = scan[(long)b * C + c];
  __syncthreads();
  int e0 = c * CS, e1 = min(E, e0 + CS);
  bool is64 = meta[0] != 0;
  unsigned spb1 = (1u << shift) - 1u;
  for (int e = e0 + threadIdx.x; e < e1; e += 256) {
    int s, d;
    if (is64) {
      const long long* p = (const long long*)ei;
      s = (int)p[e]; d = (int)p[(long)E + e];
    } else {
      const int* p = (const int*)ei;
      s = p[e]; d = p[(long)E + e];
    }
    int pos = atomicAdd(&cur[d >> shift], 1);
    pairs[pos] = (((unsigned)d & spb1) << SB) | (unsigned)s;
  }
}

// P4 (fused): per-bucket degree hist -> cnt, dis, rs; LDS exclusive scan;
// cursors stay in LDS; scatter src into final CSR.
__global__ __launch_bounds__(256) void k_bucketbuild(const unsigned* __restrict__ pairs,
                                                     const int* __restrict__ scan,
                                                     int C, int shift, int SB, int N,
                                                     int* __restrict__ cnt,
                                                     float* __restrict__ dis,
                                                     int* __restrict__ rs,
                                                     int* __restrict__ csr) {
  __shared__ int h[1024];
  __shared__ int sm[256];
  int bin = blockIdx.x;
  int base = bin << shift;
  int nn = min(N - base, 1 << shift);
  int t = threadIdx.x;
  unsigned smask = (1u << SB) - 1u;
  for (int i = t; i < 1024; i += 256) h[i] = 0;
  __syncthreads();
  int p0 = scan[(long)bin * C];
  int p1 = scan[(long)(bin + 1) * C];  // sentinel row gives E for last bucket
  for (int i = p0 + t; i < p1; i += 256)
    atomicAdd(&h[pairs[i] >> SB], 1);
  __syncthreads();
  int v0 = h[4 * t], v1 = h[4 * t + 1], v2 = h[4 * t + 2], v3 = h[4 * t + 3];
  int s = v0 + v1 + v2 + v3;
  sm[t] = s;
  __syncthreads();
  for (int off = 1; off < 256; off <<= 1) {
    int x = (t >= off) ? sm[t - off] : 0;
    __syncthreads();
    sm[t] += x;
    __syncthreads();
  }
  int run = p0 + sm[t] - s;
  int r0 = run, r1 = run + v0, r2 = r1 + v1, r3 = r2 + v2;
  h[4 * t] = r0; h[4 * t + 1] = r1; h[4 * t + 2] = r2; h[4 * t + 3] = r3;
  if (4 * t + 0 < nn) { cnt[base + 4*t+0] = v0; dis[base + 4*t+0] = rsqrtf((float)v0 + 1.f); rs[base + 4*t+0] = r0; }
  if (4 * t + 1 < nn) { cnt[base + 4*t+1] = v1; dis[base + 4*t+1] = rsqrtf((float)v1 + 1.f); rs[base + 4*t+1] = r1; }
  if (4 * t + 2 < nn) { cnt[base + 4*t+2] = v2; dis[base + 4*t+2] = rsqrtf((float)v2 + 1.f); rs[base + 4*t+2] = r2; }
  if (4 * t + 3 < nn) { cnt[base + 4*t+3] = v3; dis[base + 4*t+3] = rsqrtf((float)v3 + 1.f); rs[base + 4*t+3] = r3; }
  __syncthreads();
  for (int i = p0 + t; i < p1; i += 256) {
    unsigned p = pairs[i];
    int pos = atomicAdd(&h[p >> SB], 1);
    csr[pos] = (int)(p & smask);
  }
}

__global__ __launch_bounds__(1024) void k_scan1(const int* __restrict__ cnt,
                                                int* __restrict__ bsums, int n) {
  __shared__ int sm[1024];
  int t = threadIdx.x;
  long i = (long)blockIdx.x * 1024 + t;
  sm[t] = (i < n) ? cnt[i] : 0;
  __syncthreads();
  for (int s = 512; s > 0; s >>= 1) {
    if (t < s) sm[t] += sm[t + s];
    __syncthreads();
  }
  if (t == 0) bsums[blockIdx.x] = sm[0];
}

__global__ void k_scan2(int* __restrict__ bsums, int nb) {
  __shared__ int sm[128];
  int t = threadIdx.x;
  int v = (t < nb) ? bsums[t] : 0;
  sm[t] = v;
  __syncthreads();
  for (int off = 1; off < 128; off <<= 1) {
    int x = (t >= off) ? sm[t - off] : 0;
    __syncthreads();
    sm[t] += x;
    __syncthreads();
  }
  if (t < nb) bsums[t] = sm[t] - v;  // exclusive
}

// exclusive scan -> out (may alias in); optional sentinel out[n] = total.
__global__ __launch_bounds__(1024) void k_scan3s(const int* __restrict__ in,
                                                 const int* __restrict__ bsums,
                                                 int* __restrict__ out, int n,
                                                 int sentinel) {
  __shared__ int sm[1024];
  int t = threadIdx.x;
  long i = (long)blockIdx.x * 1024 + t;
  int v = (i < n) ? in[i] : 0;
  sm[t] = v;
  __syncthreads();
  for (int off = 1; off < 1024; off <<= 1) {
    int x = (t >= off) ? sm[t - off] : 0;
    __syncthreads();
    sm[t] += x;
    __syncthreads();
  }
  int excl = sm[t] - v + bsums[blockIdx.x];
  if (i < n) out[i] = excl;
  if (sentinel && i == n - 1) out[n] = excl + v;
}

__device__ __forceinline__ float bfu(unsigned short u) {
  return __uint_as_float((unsigned)u << 16);
}
__device__ __forceinline__ float bf_lo(unsigned u) {
  return __uint_as_float(u << 16);
}
__device__ __forceinline__ float bf_hi(unsigned u) {
  return __uint_as_float(u & 0xffff0000u);
}
__device__ __forceinline__ unsigned pack_bf2(float lo, float hi) {
  __hip_bfloat16 a = __float2bfloat16(lo), b = __float2bfloat16(hi);
  return (unsigned)*(unsigned short*)&a | ((unsigned)*(unsigned short*)&b << 16);
}

// C[n, M] = act(A[n, K] @ W[K, M] (+ bias)); W row-major [K][M], staged in LDS.
// K-loop pinned to no-unroll + manual next-k prefetch.
// ABF16: A rows bf16. ASLICE: A is slice-major bf16 [8][nrows][K/16 uints].
// OM: 0 = fp32 row-major, 1 = bf16 row-major, 2 = bf16 slice-major (M=64).
template <int K, int M, bool BIAS, int ACT, bool ABF16, bool ASLICE, int OM>
__global__ __launch_bounds__(256) void k_gemm(const void* __restrict__ Av,
                                              const float* __restrict__ W,
                                              const float* __restrict__ bias,
                                              void* __restrict__ Cout, int nrows) {
  constexpr int CP = 4;
  constexpr int TPR = M / CP;        // threads per row
  constexpr int RG = 256 / TPR;      // row-groups per block
  constexpr int RP = 4;              // rows per thread
  constexpr int RT = RG * RP;        // rows per block
  __shared__ __align__(16) float sW[K * M];
  __shared__ __align__(16) float sB[BIAS ? M : 4];

  for (int i = threadIdx.x; i < K * M / 4; i += 256)
    ((float4*)sW)[i] = ((const float4*)W)[i];
  if (BIAS)
    for (int i = threadIdx.x; i < M; i += 256) sB[i] = bias[i];
  __syncthreads();

  const int cg = threadIdx.x % TPR;
  const int rg = threadIdx.x / TPR;
  const long row0 = (long)blockIdx.x * RT + rg;

  const float4* Apf[RP];
  const ushort4* Apb[RP];
  long rowi[RP];
  bool valid[RP];
#pragma unroll
  for (int r = 0; r < RP; ++r) {
    long row = row0 + (long)r * RG;
    valid[r] = (row < nrows);
    long rr = valid[r] ? row : 0;
    rowi[r] = rr;
    if (ABF16) Apb[r] = (const ushort4*)((const unsigned short*)Av + rr * K);
    else       Apf[r] = (const float4*)((const float*)Av + rr * K);
  }

  auto loadA = [&](int r, int k4) -> float4 {
    if (!valid[r]) return make_float4(0.f, 0.f, 0.f, 0.f);
    if (ABF16) {
      if (ASLICE) {
        const unsigned* bu = (const unsigned*)Av;
        uint2 q2 = *(const uint2*)(bu + (size_t)(k4 >> 1) * nrows * 4 +
                                   rowi[r] * 4 + (k4 & 1) * 2);
        return make_float4(bf_lo(q2.x), bf_hi(q2.x), bf_lo(q2.y), bf_hi(q2.y));
      }
      ushort4 q = Apb[r][k4];
      return make_float4(bfu(q.x), bfu(q.y), bfu(q.z), bfu(q.w));
    }
    return Apf[r][k4];
  };

  float acc[RP][CP] = {};
  float4 a[RP];
#pragma unroll
  for (int r = 0; r < RP; ++r) a[r] = loadA(r, 0);

#pragma unroll 1
  for (int k0 = 0; k0 < K - 4; k0 += 4) {
    float4 an[RP];
#pragma unroll
    for (int r = 0; r < RP; ++r) an[r] = loadA(r, k0 / 4 + 1);
#pragma unroll
    for (int j = 0; j < 4; ++j) {
      float4 w = ((const float4*)(sW + (k0 + j) * M))[cg];
#pragma unroll
      for (int r = 0; r < RP; ++r) {
        float av = (j == 0) ? a[r].x : (j == 1) ? a[r].y : (j == 2) ? a[r].z : a[r].w;
        acc[r][0] += av * w.x;
        acc[r][1] += av * w.y;
        acc[r][2] += av * w.z;
        acc[r][3] += av * w.w;
      }
    }
#pragma unroll
    for (int r = 0; r < RP; ++r) a[r] = an[r];
  }
  {  // last k-step
    const int k0 = K - 4;
#pragma unroll
    for (int j = 0; j < 4; ++j) {
      float4 w = ((const float4*)(sW + (k0 + j) * M))[cg];
#pragma unroll
      for (int r = 0; r < RP; ++r) {
        float av = (j == 0) ? a[r].x : (j == 1) ? a[r].y : (j == 2) ? a[r].z : a[r].w;
        acc[r][0] += av * w.x;
        acc[r][1] += av * w.y;
        acc[r][2] += av * w.z;
        acc[r][3] += av * w.w;
      }
    }
  }

#pragma unroll
  for (int r = 0; r < RP; ++r) {
    long row = row0 + (long)r * RG;
    if (row >= nrows) continue;
    float4 o = make_float4(acc[r][0], acc[r][1], acc[r][2], acc[r][3]);
    if (BIAS) {
      float4 bb = ((const float4*)sB)[cg];
      o.x += bb.x; o.y += bb.y; o.z += bb.z; o.w += bb.w;
    }
    if (ACT == 1) {
      o.x = fmaxf(o.x, 0.f); o.y = fmaxf(o.y, 0.f);
      o.z = fmaxf(o.z, 0.f); o.w = fmaxf(o.w, 0.f);
    }
    if (OM == 1) {
      uint2 pk;
      pk.x = pack_bf2(o.x, o.y);
      pk.y = pack_bf2(o.z, o.w);
      ((uint2*)((__hip_bfloat16*)Cout + row * M))[cg] = pk;
    } else if (OM == 2) {
      // bf16 slice-major (M==64): [8][nrows][4 uints]; slice = cg/2
      unsigned* ou = (unsigned*)Cout;
      uint2 pk;
      pk.x = pack_bf2(o.x, o.y);
      pk.y = pack_bf2(o.z, o.w);
      *(uint2*)(ou + (size_t)(cg >> 1) * nrows * 4 + row * 4 + (cg & 1) * 2) = pk;
    } else {
      ((float4*)((float*)Cout + row * M))[cg] = o;
    }
  }
}

// XCD-sliced pull agg, D=64: feature-slice = blockIdx&7 (maps to XCD via
// round-robin dispatch); node range = (blockIdx>>3)*NR. 4 lanes/node
// (1 uint = 2 feats each), 64 groups/block, unroll 8, register acc.
// Reads hw1s slice-major [8][N][4]; writes h1s slice-major [8][N][4].
__global__ __launch_bounds__(256) void k_agg64s(const unsigned* __restrict__ hws,
                                                const int* __restrict__ csr,
                                                const int* __restrict__ rs,
                                                const int* __restrict__ cnt,
                                                const float* __restrict__ dis,
                                                const float* __restrict__ b,
                                                unsigned* __restrict__ outs,
                                                int N, int NR) {
  int slice = blockIdx.x & 7;
  int r0 = (blockIdx.x >> 3) * NR;
  int rend = min(r0 + NR, N);
  const unsigned* hs = hws + (size_t)slice * N * 4;
  unsigned* os = outs + (size_t)slice * N * 4;
  int l4 = threadIdx.x & 3;
  float b0 = b[slice * 8 + l4 * 2];
  float b1 = b[slice * 8 + l4 * 2 + 1];
  for (int node = r0 + (threadIdx.x >> 2); node < rend; node += 64) {
    float dsn = dis[node];
    unsigned sq = hs[(unsigned)node * 4u + l4];
    float d2 = dsn * dsn;
    float a0 = bf_lo(sq) * d2, a1 = bf_hi(sq) * d2;
    int st = rs[node], deg = cnt[node];
    int e = 0;
    for (; e + 7 < deg; e += 8) {
      int s0 = csr[st + e],     s1 = csr[st + e + 1];
      int s2 = csr[st + e + 2], s3 = csr[st + e + 3];
      int s4 = csr[st + e + 4], s5 = csr[st + e + 5];
      int s6 = csr[st + e + 6], s7 = csr[st + e + 7];
      float w0 = dis[s0] * dsn, w1 = dis[s1] * dsn;
      float w2 = dis[s2] * dsn, w3 = dis[s3] * dsn;
      float w4 = dis[s4] * dsn, w5 = dis[s5] * dsn;
      float w6 = dis[s6] * dsn, w7 = dis[s7] * dsn;
      unsigned q0 = hs[(unsigned)s0 * 4u + l4];
      unsigned q1 = hs[(unsigned)s1 * 4u + l4];
      unsigned q2 = hs[(unsigned)s2 * 4u + l4];
      unsigned q3 = hs[(unsigned)s3 * 4u + l4];
      unsigned q4 = hs[(unsigned)s4 * 4u + l4];
      unsigned q5 = hs[(unsigned)s5 * 4u + l4];
      unsigned q6 = hs[(unsigned)s6 * 4u + l4];
      unsigned q7 = hs[(unsigned)s7 * 4u + l4];
      a0 += bf_lo(q0) * w0 + bf_lo(q1) * w1 + bf_lo(q2) * w2 + bf_lo(q3) * w3
          + bf_lo(q4) * w4 + bf_lo(q5) * w5 + bf_lo(q6) * w6 + bf_lo(q7) * w7;
      a1 += bf_hi(q0) * w0 + bf_hi(q1) * w1 + bf_hi(q2) * w2 + bf_hi(q3) * w3
          + bf_hi(q4) * w4 + bf_hi(q5) * w5 + bf_hi(q6) * w6 + bf_hi(q7) * w7;
    }
    for (; e < deg; ++e) {
      int s0 = csr[st + e];
      float w0 = dis[s0] * dsn;
      unsigned q0 = hs[(unsigned)s0 * 4u + l4];
      a0 += bf_lo(q0) * w0;
      a1 += bf_hi(q0) * w0;
    }
    os[(unsigned)node * 4u + l4] =
        pack_bf2(fmaxf(a0 + b0, 0.f), fmaxf(a1 + b1, 0.f));
  }
}

// Pull aggregation, D=32 bf16 (round-8 structure): 8 lanes/node (uint2 =
// 4 feats per lane), 8 nodes/wave, unroll 8. fp32 output -> d_out.
__global__ __launch_bounds__(256) void k_agg32p(const uint2* __restrict__ hw,
                                                const int* __restrict__ csr,
                                                const int* __restrict__ rs,
                                                const int* __restrict__ cnt,
                                                const float* __restrict__ dis,
                                                const float* __restrict__ b,
                                                float* __restrict__ out, int n) {
  unsigned node = blockIdx.x * 32u + (threadIdx.x >> 3);
  if (node >= (unsigned)n) return;
  unsigned f4 = threadIdx.x & 7;
  float dsn = dis[node];
  uint2 su = hw[node * 8u + f4];
  float d2 = dsn * dsn;
  float a0 = bf_lo(su.x) * d2, a1 = bf_hi(su.x) * d2;
  float a2 = bf_lo(su.y) * d2, a3 = bf_hi(su.y) * d2;
  int start = rs[node], deg = cnt[node];
  int e = 0;
  for (; e + 7 < deg; e += 8) {
    unsigned s0 = (unsigned)csr[start + e];
    unsigned s1 = (unsigned)csr[start + e + 1];
    unsigned s2 = (unsigned)csr[start + e + 2];
    unsigned s3 = (unsigned)csr[start + e + 3];
    unsigned s4 = (unsigned)csr[start + e + 4];
    unsigned s5 = (unsigned)csr[start + e + 5];
    unsigned s6 = (unsigned)csr[start + e + 6];
    unsigned s7 = (unsigned)csr[start + e + 7];
    float w0 = dis[s0] * dsn, w1 = dis[s1] * dsn;
    float w2 = dis[s2] * dsn, w3 = dis[s3] * dsn;
    float w4 = dis[s4] * dsn, w5 = dis[s5] * dsn;
    float w6 = dis[s6] * dsn, w7 = dis[s7] * dsn;
    uint2 u0 = hw[s0 * 8u + f4];
    uint2 u1 = hw[s1 * 8u + f4];
    uint2 u2 = hw[s2 * 8u + f4];
    uint2 u3 = hw[s3 * 8u + f4];
    uint2 u4 = hw[s4 * 8u + f4];
    uint2 u5 = hw[s5 * 8u + f4];
    uint2 u6 = hw[s6 * 8u + f4];
    uint2 u7 = hw[s7 * 8u + f4];
    a0 += bf_lo(u0.x) * w0 + bf_lo(u1.x) * w1 + bf_lo(u2.x) * w2 + bf_lo(u3.x) * w3
        + bf_lo(u4.x) * w4 + bf_lo(u5.x) * w5 + bf_lo(u6.x) * w6 + bf_lo(u7.x) * w7;
    a1 += bf_hi(u0.x) * w0 + bf_hi(u1.x) * w1 + bf_hi(u2.x) * w2 + bf_hi(u3.x) * w3
        + bf_hi(u4.x) * w4 + bf_hi(u5.x) * w5 + bf_hi(u6.x) * w6 + bf_hi(u7.x) * w7;
    a2 += bf_lo(u0.y) * w0 + bf_lo(u1.y) * w1 + bf_lo(u2.y) * w2 + bf_lo(u3.y) * w3
        + bf_lo(u4.y) * w4 + bf_lo(u5.y) * w5 + bf_lo(u6.y) * w6 + bf_lo(u7.y) * w7;
    a3 += bf_hi(u0.y) * w0 + bf_hi(u1.y) * w1 + bf_hi(u2.y) * w2 + bf_hi(u3.y) * w3
        + bf_hi(u4.y) * w4 + bf_hi(u5.y) * w5 + bf_hi(u6.y) * w6 + bf_hi(u7.y) * w7;
  }
  for (; e < deg; ++e) {
    unsigned s0 = (unsigned)csr[start + e];
    float w0 = dis[s0] * dsn;
    uint2 u0 = hw[s0 * 8u + f4];
    a0 += bf_lo(u0.x) * w0;
    a1 += bf_hi(u0.x) * w0;
    a2 += bf_lo(u0.y) * w0;
    a3 += bf_hi(u0.y) * w0;
  }
  float4 bb = ((const float4*)b)[f4];
  ((float4*)(out + node * 32u))[f4] =
      make_float4(a0 + bb.x, a1 + bb.y, a2 + bb.z, a3 + bb.w);
}

// score = sigmoid(s[N,32] @ sW2[32] + sb2); 8 nodes per 256-thread block.
__global__ void k_score(const float* __restrict__ s, const float* __restrict__ sW2,
                        const float* __restrict__ sb2, float* __restrict__ out, int n) {
  int node = blockIdx.x * 8 + (threadIdx.x >> 5);
  int k = threadIdx.x & 31;
  if (node >= n) return;
  float v = s[(long)node * 32 + k] * sW2[k];
  for (int off = 16; off > 0; off >>= 1) v += __shfl_down(v, off, 32);
  if (k == 0) out[node] = 1.0f / (1.0f + expf(-(v + sb2[0])));
}

extern "C" void kernel_launch(void* const* d_in, const int* in_sizes, int n_in,
                              void* d_out, int out_size, void* d_ws, size_t ws_size,
                              hipStream_t stream) {
  const float* x   = (const float*)d_in[0];
  const void*  ei  = d_in[1];
  const float* W1  = (const float*)d_in[2];
  const float* b1  = (const float*)d_in[3];
  const float* W2  = (const float*)d_in[4];
  const float* b2  = (const float*)d_in[5];
  const float* rW1 = (const float*)d_in[6];
  const float* rb1 = (const float*)d_in[7];
  const float* rW2 = (const float*)d_in[8];
  const float* rb2 = (const float*)d_in[9];
  const float* sW1 = (const float*)d_in[10];
  const float* sb1 = (const float*)d_in[11];
  const float* sW2 = (const float*)d_in[12];
  const float* sb2 = (const float*)d_in[13];

  const int N = in_sizes[0] / 128;
  const int E = in_sizes[1] / 2;

  // bucket geometry: SPB = 1<<shift nodes per bucket, B buckets (<=256)
  int shift = 9;
  while ((((long)N + (1L << shift) - 1) >> shift) > 256) ++shift;
  const int SB = 32 - shift;               // src bits in packed pair
  const int B = (int)(((long)N + (1L << shift) - 1) >> shift);
  const int C = 512;                       // edge chunks
  const int CS = (E + C - 1) / C;          // edges per chunk
  const int L = B * C;

  // workspace layout (256B aligned chunks)
  char* w = (char*)d_ws;
  auto alloc = [&](size_t bytes) {
    char* p = w;
    w += (bytes + 255) & ~(size_t)255;
    return p;
  };
  int*   meta   = (int*)alloc(64);
  int*   cnt    = (int*)alloc((size_t)N * 4);
  int*   rs     = (int*)alloc((size_t)N * 4);
  float* dis    = (float*)alloc((size_t)N * 4);
  int*   bsumsL = (int*)alloc(1024);
  int*   bscan  = (int*)alloc(((size_t)L + 1) * 4);
  int*   csr    = (int*)alloc((size_t)E * 4);
  // union buffer: pairs (E*4B packed) -> later tbuf bf16 [N,64] / sbuf fp32 [N,32]
  size_t uni = (size_t)E * 4 > (size_t)N * 128 ? (size_t)E * 4 : (size_t)N * 128;
  char*  u      = alloc(uni);
  unsigned* pairs = (unsigned*)u;
  __hip_bfloat16* tbuf = (__hip_bfloat16*)u;   // recon intermediate [N,64] bf16
  float* sbuf   = (float*)u;                   // scorer intermediate [N,32] fp32
  unsigned* hw1s = (unsigned*)alloc((size_t)N * 128);  // bf16 slice-major [8][N][4 uints]
  unsigned* h1s  = (unsigned*)alloc((size_t)N * 128);  // bf16 slice-major [8][N][4 uints]
  uint2*    hw2  = (uint2*)alloc((size_t)N * 64);      // bf16 row-major [N][32]

  float* h_out = (float*)d_out;                 // [N,32]
  float* x_rec = h_out + (long)N * 32;          // [N,128]
  float* score = x_rec + (long)N * 128;         // [N,1]

  // ---- CSR build (atomic-free two-level counting sort, packed u32 pairs) ----
  k_detect<<<1, 256, 0, stream>>>((const unsigned int*)ei, E < 4096 ? E : 4096, meta);
  k_binhist<<<C, 256, 0, stream>>>(ei, E, CS, B, shift, meta, bscan, C);
  int nbL = (L + 1023) / 1024;
  k_scan1<<<nbL, 1024, 0, stream>>>(bscan, bsumsL, L);
  k_scan2<<<1, 128, 0, stream>>>(bsumsL, nbL);
  k_scan3s<<<nbL, 1024, 0, stream>>>(bscan, bsumsL, bscan, L, 1);  // in-place + sentinel
  k_binscatter<<<C, 256, 0, stream>>>(ei, E, CS, B, shift, SB, meta, bscan, C, pairs);
  k_bucketbuild<<<B, 256, 0, stream>>>(pairs, bscan, C, shift, SB, N, cnt, dis, rs, csr);

  // ---- layer 1: hw1s = bf16(x @ W1) slice-major ; h1s = sliced agg ----
  const int NRs = 512;
  const int Rs = (N + NRs - 1) / NRs;
  k_gemm<128, 64, false, 0, false, false, 2><<<(N + 63) / 64, 256, 0, stream>>>(x, W1, nullptr, hw1s, N);
  k_agg64s<<<8 * Rs, 256, 0, stream>>>(hw1s, csr, rs, cnt, dis, b1, h1s, N, NRs);

  // ---- layer 2: hw2 = bf16(h1s @ W2) ; h = agg + b2 -> d_out ----
  k_gemm<64, 32, false, 0, true, true, 1><<<(N + 127) / 128, 256, 0, stream>>>(h1s, W2, nullptr, hw2, N);
  k_agg32p<<<(N + 31) / 32, 256, 0, stream>>>(hw2, csr, rs, cnt, dis, b2, h_out, N);

  // ---- reconstruction MLP: t = bf16(relu(h@rW1+rb1)) ; x_rec = t@rW2+rb2 ----
  k_gemm<32, 64, true, 1, false, false, 1><<<(N + 63) / 64, 256, 0, stream>>>(h_out, rW1, rb1, tbuf, N);
  k_gemm<64, 128, true, 0, true, false, 0><<<(N + 31) / 32, 256, 0, stream>>>(tbuf, rW2, rb2, x_rec, N);

  // ---- scorer MLP: s = relu(h@sW1+sb1) ; score = sigmoid(s@sW2+sb2) ----
  k_gemm<32, 32, true, 1, false, false, 0><<<(N + 127) / 128, 256, 0, stream>>>(h_out, sW1, sb1, sbuf, N);
  k_score<<<(N + 7) / 8, 256, 0, stream>>>(sbuf, sW2, sb2, score, N);
}

// Round 13
// 298.240 us; speedup vs baseline: 7.5801x; 1.7816x over previous
//
#include <hip/hip_runtime.h>
#include <hip/hip_bf16.h>
#include <math.h>

// ---------------------------------------------------------------------------
// GCN anomaly detector.
// Rounds 9-12 established: the layer-1 gather's 62us (round-8 structure,
// 165MB L2-miss @ 2.7 TB/s) is near the practical floor -- all three
// locality structures (windows, sorted-passive, XCD-slicing) cut traffic to
// ~66MB but cost 4x in execution efficiency; max theoretical locality gain
// (~25us) < machinery cost. Round 13: revert to the round-10 pipeline and
// FUSE THE TAIL: recon MLP (2 GEMMs) + scorer MLP + score reduce into one
// k_tail kernel (weights in LDS, h staged once with padded strides, t/s
// never touch global). Kills tbuf/sbuf round-trips (~51MB), 2 extra h reads
// (~26MB), and 3 kernel launches; t stays fp32 (was bf16).
// ---------------------------------------------------------------------------

__global__ void k_detect(const unsigned int* __restrict__ w, int npairs,
                         int* __restrict__ meta) {
  __shared__ int any;
  if (threadIdx.x == 0) any = 0;
  __syncthreads();
  int local = 0;
  for (int i = threadIdx.x; i < npairs; i += blockDim.x)
    local |= (w[2 * i + 1] != 0u);
  if (local) atomicOr(&any, 1);
  __syncthreads();
  if (threadIdx.x == 0) meta[0] = any ? 0 : 1;  // 1 => edge_index is int64
}

// P1: per-chunk LDS histogram over dst buckets. hist layout: [bin][chunk].
__global__ __launch_bounds__(256) void k_binhist(const void* __restrict__ ei,
                                                 int E, int CS, int B, int shift,
                                                 const int* __restrict__ meta,
                                                 int* __restrict__ hist, int C) {
  __shared__ int lh[256];
  int c = blockIdx.x;
  for (int i = threadIdx.x; i < B; i += 256) lh[i] = 0;
  __syncthreads();
  int e0 = c * CS, e1 = min(E, e0 + CS);
  bool is64 = meta[0] != 0;
  for (int e = e0 + threadIdx.x; e < e1; e += 256) {
    int d = is64 ? (int)((const long long*)ei)[(long)E + e]
                 : ((const int*)ei)[(long)E + e];
    atomicAdd(&lh[d >> shift], 1);
  }
  __syncthreads();
  for (int b = threadIdx.x; b < B; b += 256) hist[(long)b * C + c] = lh[b];
}

// P3: re-read edges, write packed (dstInBucket<<SB | src) into reserved
// per-(chunk,bin) ranges. LDS cursors only -> zero global atomics.
__global__ __launch_bounds__(256) void k_binscatter(const void* __restrict__ ei,
                                                    int E, int CS, int B, int shift,
                                                    int SB,
                                                    const int* __restrict__ meta,
                                                    const int* __restrict__ scan,
                                                    int C, unsigned* __restrict__ pairs) {
  __shared__ int cur[256];
  int c = blockIdx.x;
  for (int b = threadIdx.x; b < B; b += 256) cur[b] = scan[(long)b * C + c];
  __syncthreads();
  int e0 = c * CS, e1 = min(E, e0 + CS);
  bool is64 = meta[0] != 0;
  unsigned spb1 = (1u << shift) - 1u;
  for (int e = e0 + threadIdx.x; e < e1; e += 256) {
    int s, d;
    if (is64) {
      const long long* p = (const long long*)ei;
      s = (int)p[e]; d = (int)p[(long)E + e];
    } else {
      const int* p = (const int*)ei;
      s = p[e]; d = p[(long)E + e];
    }
    int pos = atomicAdd(&cur[d >> shift], 1);
    pairs[pos] = (((unsigned)d & spb1) << SB) | (unsigned)s;
  }
}

// P4 (fused): per-bucket degree hist -> cnt, dis, rs; then in-LDS counting
// sort by src-bin so each dst's CSR list comes out ~src-ascending; scatter
// via LDS cursors. Overflow falls back to unsorted (still correct).
#define BB_CAP 16896
__global__ __launch_bounds__(256) void k_bucketbuild(const unsigned* __restrict__ pairs,
                                                     const int* __restrict__ scan,
                                                     int C, int shift, int SB, int N,
                                                     int* __restrict__ cnt,
                                                     float* __restrict__ dis,
                                                     int* __restrict__ rs,
                                                     int* __restrict__ csr) {
  __shared__ unsigned buf[BB_CAP];    // 66 KB
  __shared__ unsigned buf2[BB_CAP];   // 66 KB
  __shared__ int h[1024];
  __shared__ int sm[256];
  __shared__ int sh[512];
  int bin = blockIdx.x;
  int base = bin << shift;
  int nn = min(N - base, 1 << shift);
  int t = threadIdx.x;
  unsigned smask = (1u << SB) - 1u;
  int p0 = scan[(long)bin * C];
  int p1 = scan[(long)(bin + 1) * C];  // sentinel row gives E for last bucket
  int ne = p1 - p0;
  bool srt = (ne <= BB_CAP);

  if (srt)
    for (int i = t; i < ne; i += 256) buf[i] = pairs[p0 + i];
  for (int i = t; i < 1024; i += 256) h[i] = 0;
  __syncthreads();

  for (int i = t; i < ne; i += 256)
    atomicAdd(&h[(srt ? buf[i] : pairs[p0 + i]) >> SB], 1);
  __syncthreads();

  int v0 = h[4 * t], v1 = h[4 * t + 1], v2 = h[4 * t + 2], v3 = h[4 * t + 3];
  int s = v0 + v1 + v2 + v3;
  sm[t] = s;
  __syncthreads();
  for (int off = 1; off < 256; off <<= 1) {
    int x = (t >= off) ? sm[t - off] : 0;
    __syncthreads();
    sm[t] += x;
    __syncthreads();
  }
  int run = p0 + sm[t] - s;
  int r0 = run, r1 = run + v0, r2 = r1 + v1, r3 = r2 + v2;
  h[4 * t] = r0; h[4 * t + 1] = r1; h[4 * t + 2] = r2; h[4 * t + 3] = r3;
  if (4 * t + 0 < nn) { cnt[base + 4*t+0] = v0; dis[base + 4*t+0] = rsqrtf((float)v0 + 1.f); rs[base + 4*t+0] = r0; }
  if (4 * t + 1 < nn) { cnt[base + 4*t+1] = v1; dis[base + 4*t+1] = rsqrtf((float)v1 + 1.f); rs[base + 4*t+1] = r1; }
  if (4 * t + 2 < nn) { cnt[base + 4*t+2] = v2; dis[base + 4*t+2] = rsqrtf((float)v2 + 1.f); rs[base + 4*t+2] = r2; }
  if (4 * t + 3 < nn) { cnt[base + 4*t+3] = v3; dis[base + 4*t+3] = rsqrtf((float)v3 + 1.f); rs[base + 4*t+3] = r3; }
  __syncthreads();

  if (srt) {
    for (int i = t; i < 512; i += 256) sh[i] = 0;
    __syncthreads();
    for (int i = t; i < ne; i += 256)
      atomicAdd(&sh[(buf[i] & smask) >> 8], 1);
    __syncthreads();
    int a0 = sh[2 * t], a1 = sh[2 * t + 1];
    int ss = a0 + a1;
    sm[t] = ss;
    __syncthreads();
    for (int off = 1; off < 256; off <<= 1) {
      int x = (t >= off) ? sm[t - off] : 0;
      __syncthreads();
      sm[t] += x;
      __syncthreads();
    }
    int rn = sm[t] - ss;
    sh[2 * t] = rn; sh[2 * t + 1] = rn + a0;
    __syncthreads();
    for (int i = t; i < ne; i += 256) {
      unsigned p = buf[i];
      int pos = atomicAdd(&sh[(p & smask) >> 8], 1);
      buf2[pos] = p;
    }
    __syncthreads();
    for (int i = t; i < ne; i += 256) {
      unsigned p = buf2[i];
      int pos = atomicAdd(&h[p >> SB], 1);
      csr[pos] = (int)(p & smask);
    }
  } else {
    for (int i = p0 + t; i < p1; i += 256) {
      unsigned p = pairs[i];
      int pos = atomicAdd(&h[p >> SB], 1);
      csr[pos] = (int)(p & smask);
    }
  }
}

__global__ __launch_bounds__(1024) void k_scan1(const int* __restrict__ cnt,
                                                int* __restrict__ bsums, int n) {
  __shared__ int sm[1024];
  int t = threadIdx.x;
  long i = (long)blockIdx.x * 1024 + t;
  sm[t] = (i < n) ? cnt[i] : 0;
  __syncthreads();
  for (int s = 512; s > 0; s >>= 1) {
    if (t < s) sm[t] += sm[t + s];
    __syncthreads();
  }
  if (t == 0) bsums[blockIdx.x] = sm[0];
}

__global__ void k_scan2(int* __restrict__ bsums, int nb) {
  __shared__ int sm[128];
  int t = threadIdx.x;
  int v = (t < nb) ? bsums[t] : 0;
  sm[t] = v;
  __syncthreads();
  for (int off = 1; off < 128; off <<= 1) {
    int x = (t >= off) ? sm[t - off] : 0;
    __syncthreads();
    sm[t] += x;
    __syncthreads();
  }
  if (t < nb) bsums[t] = sm[t] - v;  // exclusive
}

// exclusive scan -> out (may alias in); optional sentinel out[n] = total.
__global__ __launch_bounds__(1024) void k_scan3s(const int* __restrict__ in,
                                                 const int* __restrict__ bsums,
                                                 int* __restrict__ out, int n,
                                                 int sentinel) {
  __shared__ int sm[1024];
  int t = threadIdx.x;
  long i = (long)blockIdx.x * 1024 + t;
  int v = (i < n) ? in[i] : 0;
  sm[t] = v;
  __syncthreads();
  for (int off = 1; off < 1024; off <<= 1) {
    int x = (t >= off) ? sm[t - off] : 0;
    __syncthreads();
    sm[t] += x;
    __syncthreads();
  }
  int excl = sm[t] - v + bsums[blockIdx.x];
  if (i < n) out[i] = excl;
  if (sentinel && i == n - 1) out[n] = excl + v;
}

__device__ __forceinline__ float bfu(unsigned short u) {
  return __uint_as_float((unsigned)u << 16);
}
__device__ __forceinline__ float bf_lo(unsigned u) {
  return __uint_as_float(u << 16);
}
__device__ __forceinline__ float bf_hi(unsigned u) {
  return __uint_as_float(u & 0xffff0000u);
}
__device__ __forceinline__ unsigned pack_bf2(float lo, float hi) {
  __hip_bfloat16 a = __float2bfloat16(lo), b = __float2bfloat16(hi);
  return (unsigned)*(unsigned short*)&a | ((unsigned)*(unsigned short*)&b << 16);
}

// C[n, M] = act(A[n, K] @ W[K, M] (+ bias)); W row-major [K][M], staged in LDS.
// K-loop pinned to no-unroll + manual next-k prefetch.
// ABF16: A rows are bf16. OBF16: write output as bf16 (RNE).
template <int K, int M, bool BIAS, int ACT, bool ABF16, bool OBF16>
__global__ __launch_bounds__(256) void k_gemm(const void* __restrict__ Av,
                                              const float* __restrict__ W,
                                              const float* __restrict__ bias,
                                              void* __restrict__ Cout, int nrows) {
  constexpr int CP = 4;
  constexpr int TPR = M / CP;        // threads per row
  constexpr int RG = 256 / TPR;      // row-groups per block
  constexpr int RP = 4;              // rows per thread
  constexpr int RT = RG * RP;        // rows per block
  __shared__ __align__(16) float sW[K * M];
  __shared__ __align__(16) float sB[BIAS ? M : 4];

  for (int i = threadIdx.x; i < K * M / 4; i += 256)
    ((float4*)sW)[i] = ((const float4*)W)[i];
  if (BIAS)
    for (int i = threadIdx.x; i < M; i += 256) sB[i] = bias[i];
  __syncthreads();

  const int cg = threadIdx.x % TPR;
  const int rg = threadIdx.x / TPR;
  const long row0 = (long)blockIdx.x * RT + rg;

  const float4* Apf[RP];
  const ushort4* Apb[RP];
  bool valid[RP];
#pragma unroll
  for (int r = 0; r < RP; ++r) {
    long row = row0 + (long)r * RG;
    valid[r] = (row < nrows);
    long rr = valid[r] ? row : 0;
    if (ABF16) Apb[r] = (const ushort4*)((const unsigned short*)Av + rr * K);
    else       Apf[r] = (const float4*)((const float*)Av + rr * K);
  }

  auto loadA = [&](int r, int k4) -> float4 {
    if (!valid[r]) return make_float4(0.f, 0.f, 0.f, 0.f);
    if (ABF16) {
      ushort4 q = Apb[r][k4];
      return make_float4(bfu(q.x), bfu(q.y), bfu(q.z), bfu(q.w));
    }
    return Apf[r][k4];
  };

  float acc[RP][CP] = {};
  float4 a[RP];
#pragma unroll
  for (int r = 0; r < RP; ++r) a[r] = loadA(r, 0);

#pragma unroll 1
  for (int k0 = 0; k0 < K - 4; k0 += 4) {
    float4 an[RP];
#pragma unroll
    for (int r = 0; r < RP; ++r) an[r] = loadA(r, k0 / 4 + 1);
#pragma unroll
    for (int j = 0; j < 4; ++j) {
      float4 w = ((const float4*)(sW + (k0 + j) * M))[cg];
#pragma unroll
      for (int r = 0; r < RP; ++r) {
        float av = (j == 0) ? a[r].x : (j == 1) ? a[r].y : (j == 2) ? a[r].z : a[r].w;
        acc[r][0] += av * w.x;
        acc[r][1] += av * w.y;
        acc[r][2] += av * w.z;
        acc[r][3] += av * w.w;
      }
    }
#pragma unroll
    for (int r = 0; r < RP; ++r) a[r] = an[r];
  }
  {  // last k-step
    const int k0 = K - 4;
#pragma unroll
    for (int j = 0; j < 4; ++j) {
      float4 w = ((const float4*)(sW + (k0 + j) * M))[cg];
#pragma unroll
      for (int r = 0; r < RP; ++r) {
        float av = (j == 0) ? a[r].x : (j == 1) ? a[r].y : (j == 2) ? a[r].z : a[r].w;
        acc[r][0] += av * w.x;
        acc[r][1] += av * w.y;
        acc[r][2] += av * w.z;
        acc[r][3] += av * w.w;
      }
    }
  }

#pragma unroll
  for (int r = 0; r < RP; ++r) {
    long row = row0 + (long)r * RG;
    if (row >= nrows) continue;
    float4 o = make_float4(acc[r][0], acc[r][1], acc[r][2], acc[r][3]);
    if (BIAS) {
      float4 bb = ((const float4*)sB)[cg];
      o.x += bb.x; o.y += bb.y; o.z += bb.z; o.w += bb.w;
    }
    if (ACT == 1) {
      o.x = fmaxf(o.x, 0.f); o.y = fmaxf(o.y, 0.f);
      o.z = fmaxf(o.z, 0.f); o.w = fmaxf(o.w, 0.f);
    }
    if (OBF16) {
      uint2 pk;
      pk.x = pack_bf2(o.x, o.y);
      pk.y = pack_bf2(o.z, o.w);
      ((uint2*)((__hip_bfloat16*)Cout + row * M))[cg] = pk;
    } else {
      ((float4*)((float*)Cout + row * M))[cg] = o;
    }
  }
}

// Pull aggregation, D=64 bf16: 16 lanes/node (4 feats = uint2 per lane),
// 4 nodes/wave, unroll 8. Output packed bf16 (uint2/lane).
__global__ __launch_bounds__(256) void k_agg64p(const uint2* __restrict__ hw,
                                                const int* __restrict__ csr,
                                                const int* __restrict__ rs,
                                                const int* __restrict__ cnt,
                                                const float* __restrict__ dis,
                                                const float* __restrict__ b,
                                                uint2* __restrict__ out, int n) {
  unsigned node = blockIdx.x * 16u + (threadIdx.x >> 4);
  if (node >= (unsigned)n) return;
  unsigned f4 = threadIdx.x & 15;
  float dsn = dis[node];
  uint2 su = hw[node * 16u + f4];
  float d2 = dsn * dsn;
  float a0 = bf_lo(su.x) * d2, a1 = bf_hi(su.x) * d2;
  float a2 = bf_lo(su.y) * d2, a3 = bf_hi(su.y) * d2;
  int start = rs[node], deg = cnt[node];
  int e = 0;
  for (; e + 7 < deg; e += 8) {
    unsigned s0 = (unsigned)csr[start + e];
    unsigned s1 = (unsigned)csr[start + e + 1];
    unsigned s2 = (unsigned)csr[start + e + 2];
    unsigned s3 = (unsigned)csr[start + e + 3];
    unsigned s4 = (unsigned)csr[start + e + 4];
    unsigned s5 = (unsigned)csr[start + e + 5];
    unsigned s6 = (unsigned)csr[start + e + 6];
    unsigned s7 = (unsigned)csr[start + e + 7];
    float w0 = dis[s0] * dsn, w1 = dis[s1] * dsn;
    float w2 = dis[s2] * dsn, w3 = dis[s3] * dsn;
    float w4 = dis[s4] * dsn, w5 = dis[s5] * dsn;
    float w6 = dis[s6] * dsn, w7 = dis[s7] * dsn;
    uint2 u0 = hw[s0 * 16u + f4];
    uint2 u1 = hw[s1 * 16u + f4];
    uint2 u2 = hw[s2 * 16u + f4];
    uint2 u3 = hw[s3 * 16u + f4];
    uint2 u4 = hw[s4 * 16u + f4];
    uint2 u5 = hw[s5 * 16u + f4];
    uint2 u6 = hw[s6 * 16u + f4];
    uint2 u7 = hw[s7 * 16u + f4];
    a0 += bf_lo(u0.x) * w0 + bf_lo(u1.x) * w1 + bf_lo(u2.x) * w2 + bf_lo(u3.x) * w3
        + bf_lo(u4.x) * w4 + bf_lo(u5.x) * w5 + bf_lo(u6.x) * w6 + bf_lo(u7.x) * w7;
    a1 += bf_hi(u0.x) * w0 + bf_hi(u1.x) * w1 + bf_hi(u2.x) * w2 + bf_hi(u3.x) * w3
        + bf_hi(u4.x) * w4 + bf_hi(u5.x) * w5 + bf_hi(u6.x) * w6 + bf_hi(u7.x) * w7;
    a2 += bf_lo(u0.y) * w0 + bf_lo(u1.y) * w1 + bf_lo(u2.y) * w2 + bf_lo(u3.y) * w3
        + bf_lo(u4.y) * w4 + bf_lo(u5.y) * w5 + bf_lo(u6.y) * w6 + bf_lo(u7.y) * w7;
    a3 += bf_hi(u0.y) * w0 + bf_hi(u1.y) * w1 + bf_hi(u2.y) * w2 + bf_hi(u3.y) * w3
        + bf_hi(u4.y) * w4 + bf_hi(u5.y) * w5 + bf_hi(u6.y) * w6 + bf_hi(u7.y) * w7;
  }
  for (; e < deg; ++e) {
    unsigned s0 = (unsigned)csr[start + e];
    float w0 = dis[s0] * dsn;
    uint2 u0 = hw[s0 * 16u + f4];
    a0 += bf_lo(u0.x) * w0;
    a1 += bf_hi(u0.x) * w0;
    a2 += bf_lo(u0.y) * w0;
    a3 += bf_hi(u0.y) * w0;
  }
  float4 bb = ((const float4*)b)[f4];
  uint2 pk;
  pk.x = pack_bf2(fmaxf(a0 + bb.x, 0.f), fmaxf(a1 + bb.y, 0.f));  // relu
  pk.y = pack_bf2(fmaxf(a2 + bb.z, 0.f), fmaxf(a3 + bb.w, 0.f));
  out[node * 16u + f4] = pk;
}

// Pull aggregation, D=32 bf16: 8 lanes/node (4 feats = uint2 per lane),
// 8 nodes/wave, unroll 8. fp32 output (this IS the h output in d_out).
__global__ __launch_bounds__(256) void k_agg32p(const uint2* __restrict__ hw,
                                                const int* __restrict__ csr,
                                                const int* __restrict__ rs,
                                                const int* __restrict__ cnt,
                                                const float* __restrict__ dis,
                                                const float* __restrict__ b,
                                                float* __restrict__ out, int n) {
  unsigned node = blockIdx.x * 32u + (threadIdx.x >> 3);
  if (node >= (unsigned)n) return;
  unsigned f4 = threadIdx.x & 7;
  float dsn = dis[node];
  uint2 su = hw[node * 8u + f4];
  float d2 = dsn * dsn;
  float a0 = bf_lo(su.x) * d2, a1 = bf_hi(su.x) * d2;
  float a2 = bf_lo(su.y) * d2, a3 = bf_hi(su.y) * d2;
  int start = rs[node], deg = cnt[node];
  int e = 0;
  for (; e + 7 < deg; e += 8) {
    unsigned s0 = (unsigned)csr[start + e];
    unsigned s1 = (unsigned)csr[start + e + 1];
    unsigned s2 = (unsigned)csr[start + e + 2];
    unsigned s3 = (unsigned)csr[start + e + 3];
    unsigned s4 = (unsigned)csr[start + e + 4];
    unsigned s5 = (unsigned)csr[start + e + 5];
    unsigned s6 = (unsigned)csr[start + e + 6];
    unsigned s7 = (unsigned)csr[start + e + 7];
    float w0 = dis[s0] * dsn, w1 = dis[s1] * dsn;
    float w2 = dis[s2] * dsn, w3 = dis[s3] * dsn;
    float w4 = dis[s4] * dsn, w5 = dis[s5] * dsn;
    float w6 = dis[s6] * dsn, w7 = dis[s7] * dsn;
    uint2 u0 = hw[s0 * 8u + f4];
    uint2 u1 = hw[s1 * 8u + f4];
    uint2 u2 = hw[s2 * 8u + f4];
    uint2 u3 = hw[s3 * 8u + f4];
    uint2 u4 = hw[s4 * 8u + f4];
    uint2 u5 = hw[s5 * 8u + f4];
    uint2 u6 = hw[s6 * 8u + f4];
    uint2 u7 = hw[s7 * 8u + f4];
    a0 += bf_lo(u0.x) * w0 + bf_lo(u1.x) * w1 + bf_lo(u2.x) * w2 + bf_lo(u3.x) * w3
        + bf_lo(u4.x) * w4 + bf_lo(u5.x) * w5 + bf_lo(u6.x) * w6 + bf_lo(u7.x) * w7;
    a1 += bf_hi(u0.x) * w0 + bf_hi(u1.x) * w1 + bf_hi(u2.x) * w2 + bf_hi(u3.x) * w3
        + bf_hi(u4.x) * w4 + bf_hi(u5.x) * w5 + bf_hi(u6.x) * w6 + bf_hi(u7.x) * w7;
    a2 += bf_lo(u0.y) * w0 + bf_lo(u1.y) * w1 + bf_lo(u2.y) * w2 + bf_lo(u3.y) * w3
        + bf_lo(u4.y) * w4 + bf_lo(u5.y) * w5 + bf_lo(u6.y) * w6 + bf_lo(u7.y) * w7;
    a3 += bf_hi(u0.y) * w0 + bf_hi(u1.y) * w1 + bf_hi(u2.y) * w2 + bf_hi(u3.y) * w3
        + bf_hi(u4.y) * w4 + bf_hi(u5.y) * w5 + bf_hi(u6.y) * w6 + bf_hi(u7.y) * w7;
  }
  for (; e < deg; ++e) {
    unsigned s0 = (unsigned)csr[start + e];
    float w0 = dis[s0] * dsn;
    uint2 u0 = hw[s0 * 8u + f4];
    a0 += bf_lo(u0.x) * w0;
    a1 += bf_hi(u0.x) * w0;
    a2 += bf_lo(u0.y) * w0;
    a3 += bf_hi(u0.y) * w0;
  }
  float4 bb = ((const float4*)b)[f4];
  ((float4*)(out + node * 32u))[f4] =
      make_float4(a0 + bb.x, a1 + bb.y, a2 + bb.z, a3 + bb.w);
}

// Fused tail: per block of 64 nodes, from h (fp32 [N,32] in d_out):
//   t = relu(h@rW1+rb1)   [64][64] LDS (fp32, never global)
//   x_rec = t@rW2+rb2     -> global fp32 [N,128]
//   s = relu(h@sW1+sb1)   [64][32] LDS
//   score = sigmoid(s.sW2+sb2) -> global [N,1]
// Padded LDS strides (33/65) kill bank conflicts on row-indexed reads.
__global__ __launch_bounds__(256) void k_tail(const float* __restrict__ h,
                                              const float* __restrict__ rW1,
                                              const float* __restrict__ rb1,
                                              const float* __restrict__ rW2,
                                              const float* __restrict__ rb2,
                                              const float* __restrict__ sW1,
                                              const float* __restrict__ sb1,
                                              const float* __restrict__ sW2,
                                              const float* __restrict__ sb2,
                                              float* __restrict__ x_rec,
                                              float* __restrict__ score, int n) {
  __shared__ __align__(16) float sRW1[32 * 64];    // 8 KB
  __shared__ __align__(16) float sRW2[64 * 128];   // 32 KB
  __shared__ __align__(16) float sSW1[32 * 32];    // 4 KB
  __shared__ __align__(16) float sRB1[64];
  __shared__ __align__(16) float sRB2[128];
  __shared__ __align__(16) float sSB1[32];
  __shared__ __align__(16) float sSW2[32];
  __shared__ float sH[64 * 33];                    // 8.45 KB
  __shared__ float sT[64 * 65];                    // 16.6 KB
  __shared__ float sS[64 * 33];                    // 8.45 KB
  int t = threadIdx.x;
  for (int i = t; i < 32 * 64 / 4; i += 256) ((float4*)sRW1)[i] = ((const float4*)rW1)[i];
  for (int i = t; i < 64 * 128 / 4; i += 256) ((float4*)sRW2)[i] = ((const float4*)rW2)[i];
  for (int i = t; i < 32 * 32 / 4; i += 256) ((float4*)sSW1)[i] = ((const float4*)sW1)[i];
  if (t < 64) sRB1[t] = rb1[t];
  else if (t < 192) sRB2[t - 64] = rb2[t - 64];
  else if (t < 224) sSB1[t - 192] = sb1[t - 192];
  else sSW2[t - 224] = sW2[t - 224];

  long base = (long)blockIdx.x * 64;
  int nn = (int)min(64L, (long)n - base);
  if (nn < 0) nn = 0;
  for (int i = t; i < 64 * 8; i += 256) {          // 512 float4 loads of h
    int node = i >> 3, q = i & 7;
    float4 v = (node < nn) ? ((const float4*)(h + (base + node) * 32))[q]
                           : make_float4(0.f, 0.f, 0.f, 0.f);
    sH[node * 33 + 4 * q]     = v.x;
    sH[node * 33 + 4 * q + 1] = v.y;
    sH[node * 33 + 4 * q + 2] = v.z;
    sH[node * 33 + 4 * q + 3] = v.w;
  }
  __syncthreads();

  {  // phase T: M=64, TPR=16, RG=16, RP=4
    int cg = t & 15, rg = t >> 4;
    float acc[4][4] = {};
    for (int k = 0; k < 32; ++k) {
      float4 w = ((const float4*)(sRW1 + k * 64))[cg];
      float a0 = sH[rg * 33 + k];
      float a1 = sH[(rg + 16) * 33 + k];
      float a2 = sH[(rg + 32) * 33 + k];
      float a3 = sH[(rg + 48) * 33 + k];
      acc[0][0] += a0 * w.x; acc[0][1] += a0 * w.y; acc[0][2] += a0 * w.z; acc[0][3] += a0 * w.w;
      acc[1][0] += a1 * w.x; acc[1][1] += a1 * w.y; acc[1][2] += a1 * w.z; acc[1][3] += a1 * w.w;
      acc[2][0] += a2 * w.x; acc[2][1] += a2 * w.y; acc[2][2] += a2 * w.z; acc[2][3] += a2 * w.w;
      acc[3][0] += a3 * w.x; acc[3][1] += a3 * w.y; acc[3][2] += a3 * w.z; acc[3][3] += a3 * w.w;
    }
    float4 bb = ((const float4*)sRB1)[cg];
#pragma unroll
    for (int m = 0; m < 4; ++m) {
      int row = rg + 16 * m;
      sT[row * 65 + 4 * cg]     = fmaxf(acc[m][0] + bb.x, 0.f);
      sT[row * 65 + 4 * cg + 1] = fmaxf(acc[m][1] + bb.y, 0.f);
      sT[row * 65 + 4 * cg + 2] = fmaxf(acc[m][2] + bb.z, 0.f);
      sT[row * 65 + 4 * cg + 3] = fmaxf(acc[m][3] + bb.w, 0.f);
    }
  }
  {  // phase S: M=32, TPR=8, RG=32, RP=2 (reads sH only; disjoint write sS)
    int cg = t & 7, rg = t >> 3;
    float acc[2][4] = {};
    for (int k = 0; k < 32; ++k) {
      float4 w = ((const float4*)(sSW1 + k * 32))[cg];
      float a0 = sH[rg * 33 + k];
      float a1 = sH[(rg + 32) * 33 + k];
      acc[0][0] += a0 * w.x; acc[0][1] += a0 * w.y; acc[0][2] += a0 * w.z; acc[0][3] += a0 * w.w;
      acc[1][0] += a1 * w.x; acc[1][1] += a1 * w.y; acc[1][2] += a1 * w.z; acc[1][3] += a1 * w.w;
    }
    float4 bb = ((const float4*)sSB1)[cg];
#pragma unroll
    for (int m = 0; m < 2; ++m) {
      int row = rg + 32 * m;
      sS[row * 33 + 4 * cg]     = fmaxf(acc[m][0] + bb.x, 0.f);
      sS[row * 33 + 4 * cg + 1] = fmaxf(acc[m][1] + bb.y, 0.f);
      sS[row * 33 + 4 * cg + 2] = fmaxf(acc[m][2] + bb.z, 0.f);
      sS[row * 33 + 4 * cg + 3] = fmaxf(acc[m][3] + bb.w, 0.f);
    }
  }
  __syncthreads();

  {  // phase X: M=128, TPR=32, RG=8, RP=8 -> x_rec global
    int cg = t & 31, rg = t >> 5;
    float acc[8][4] = {};
    for (int k = 0; k < 64; ++k) {
      float4 w = ((const float4*)(sRW2 + k * 128))[cg];
#pragma unroll
      for (int m = 0; m < 8; ++m) {
        float a = sT[(rg + 8 * m) * 65 + k];
        acc[m][0] += a * w.x; acc[m][1] += a * w.y;
        acc[m][2] += a * w.z; acc[m][3] += a * w.w;
      }
    }
    float4 bb = ((const float4*)sRB2)[cg];
#pragma unroll
    for (int m = 0; m < 8; ++m) {
      int row = rg + 8 * m;
      if (row < nn) {
        float4 o = make_float4(acc[m][0] + bb.x, acc[m][1] + bb.y,
                               acc[m][2] + bb.z, acc[m][3] + bb.w);
        ((float4*)(x_rec + (base + row) * 128))[cg] = o;
      }
    }
  }
  if (t < nn) {  // score: one thread per node
    float acc = 0.f;
    for (int j = 0; j < 32; ++j) acc += sS[t * 33 + j] * sSW2[j];
    score[base + t] = 1.0f / (1.0f + expf(-(acc + sb2[0])));
  }
}

extern "C" void kernel_launch(void* const* d_in, const int* in_sizes, int n_in,
                              void* d_out, int out_size, void* d_ws, size_t ws_size,
                              hipStream_t stream) {
  const float* x   = (const float*)d_in[0];
  const void*  ei  = d_in[1];
  const float* W1  = (const float*)d_in[2];
  const float* b1  = (const float*)d_in[3];
  const float* W2  = (const float*)d_in[4];
  const float* b2  = (const float*)d_in[5];
  const float* rW1 = (const float*)d_in[6];
  const float* rb1 = (const float*)d_in[7];
  const float* rW2 = (const float*)d_in[8];
  const float* rb2 = (const float*)d_in[9];
  const float* sW1 = (const float*)d_in[10];
  const float* sb1 = (const float*)d_in[11];
  const float* sW2 = (const float*)d_in[12];
  const float* sb2 = (const float*)d_in[13];

  const int N = in_sizes[0] / 128;
  const int E = in_sizes[1] / 2;

  // bucket geometry: SPB = 1<<shift nodes per bucket, B buckets (<=256)
  int shift = 9;
  while ((((long)N + (1L << shift) - 1) >> shift) > 256) ++shift;
  const int SB = 32 - shift;               // src bits in packed pair
  const int B = (int)(((long)N + (1L << shift) - 1) >> shift);
  const int C = 512;                       // edge chunks
  const int CS = (E + C - 1) / C;          // edges per chunk
  const int L = B * C;

  // workspace layout (256B aligned chunks)
  char* w = (char*)d_ws;
  auto alloc = [&](size_t bytes) {
    char* p = w;
    w += (bytes + 255) & ~(size_t)255;
    return p;
  };
  int*   meta   = (int*)alloc(64);
  int*   cnt    = (int*)alloc((size_t)N * 4);
  int*   rs     = (int*)alloc((size_t)N * 4);
  float* dis    = (float*)alloc((size_t)N * 4);
  int*   bsumsL = (int*)alloc(1024);
  int*   bscan  = (int*)alloc(((size_t)L + 1) * 4);
  int*   csr    = (int*)alloc((size_t)E * 4);
  unsigned* pairs = (unsigned*)alloc((size_t)E * 4);
  uint2* hw1 = (uint2*)alloc((size_t)N * 64 * 2);  // bf16 [N][64]
  uint2* h1  = (uint2*)alloc((size_t)N * 64 * 2);  // bf16 [N][64]
  uint2* hw2 = (uint2*)alloc((size_t)N * 32 * 2);  // bf16 [N][32]

  float* h_out = (float*)d_out;                 // [N,32]
  float* x_rec = h_out + (long)N * 32;          // [N,128]
  float* score = x_rec + (long)N * 128;         // [N,1]

  // ---- CSR build (atomic-free two-level counting sort, src-sorted lists) ----
  k_detect<<<1, 256, 0, stream>>>((const unsigned int*)ei, E < 4096 ? E : 4096, meta);
  k_binhist<<<C, 256, 0, stream>>>(ei, E, CS, B, shift, meta, bscan, C);
  int nbL = (L + 1023) / 1024;
  k_scan1<<<nbL, 1024, 0, stream>>>(bscan, bsumsL, L);
  k_scan2<<<1, 128, 0, stream>>>(bsumsL, nbL);
  k_scan3s<<<nbL, 1024, 0, stream>>>(bscan, bsumsL, bscan, L, 1);  // in-place + sentinel
  k_binscatter<<<C, 256, 0, stream>>>(ei, E, CS, B, shift, SB, meta, bscan, C, pairs);
  k_bucketbuild<<<B, 256, 0, stream>>>(pairs, bscan, C, shift, SB, N, cnt, dis, rs, csr);

  // ---- layer 1: hw1 = bf16(x @ W1) ; h1 = bf16(relu(agg + b1)) ----
  k_gemm<128, 64, false, 0, false, true><<<(N + 63) / 64, 256, 0, stream>>>(x, W1, nullptr, hw1, N);
  k_agg64p<<<(N + 15) / 16, 256, 0, stream>>>(hw1, csr, rs, cnt, dis, b1, h1, N);

  // ---- layer 2: hw2 = bf16(h1 @ W2) ; h = agg + b2 -> d_out ----
  k_gemm<64, 32, false, 0, true, true><<<(N + 127) / 128, 256, 0, stream>>>(h1, W2, nullptr, hw2, N);
  k_agg32p<<<(N + 31) / 32, 256, 0, stream>>>(hw2, csr, rs, cnt, dis, b2, h_out, N);

  // ---- fused tail: recon MLP + scorer MLP + score ----
  k_tail<<<(N + 63) / 64, 256, 0, stream>>>(h_out, rW1, rb1, rW2, rb2,
                                            sW1, sb1, sW2, sb2, x_rec, score, N);
}